// Round 7
// baseline (248.371 us; speedup 1.0000x reference)
//
#include <hip/hip_runtime.h>

// GraphConv: out = relu( D * A_hat * D * x * W ),  B=8, N=2048, F=O=128, fp32.
// R12: K3 wave-grid 2x2 -> 1x4 (dedup). Block = 64 rows x 128 cols; each
//   wave owns 16 rows x ALL 128 cols. A rows loaded ONCE (was 2x), B frags
//   ds_read ONCE (was 2x), B tile staged once per 64 rows (was per 32).
//   LDS bytes per output row: 48KB/32r -> 40KB/64r (2.35x better) — attacks
//   the 565-of-937-cyc LDS-BW floor that made R9/R10/R11 all neutral.
//   Grid 256 (1 block/CU). Staging, tiled yt, dbuf+syncthreads unchanged.
// K1, K2 unchanged (R11): d 1-wave/row + Wt tail; xw writes tiled yt.

typedef __bf16 bf16x8 __attribute__((ext_vector_type(8)));
typedef float  f32x4  __attribute__((ext_vector_type(4)));

#define NN 2048
#define NB 8

__device__ __forceinline__ void load_lds16(__bf16* lds, const __bf16* g) {
    // per-lane global src; LDS dest = wave-uniform base + lane*16
    __builtin_amdgcn_global_load_lds(
        (const __attribute__((address_space(1))) void*)g,
        (__attribute__((address_space(3))) void*)lds, 16, 0, 0);
}

// ---------------- K1: degree vector + Wt convert in tail blocks ----------
__global__ __launch_bounds__(256) void d_kernel(const float* __restrict__ adj,
                                                float* __restrict__ dvec,
                                                const float* __restrict__ W,
                                                __bf16* __restrict__ Wt) {
    if (blockIdx.x >= NB * NN / 4) {
        int idx = (blockIdx.x - NB * NN / 4) * 256 + threadIdx.x;
        int f = idx >> 7, o = idx & 127;
        Wt[o * 128 + f] = (__bf16)W[idx];
        return;
    }
    const int lane = threadIdx.x & 63;
    const int row  = blockIdx.x * 4 + (threadIdx.x >> 6);   // one wave per row
    const float* rp = adj + (size_t)row * NN;
    float4 s4 = {0.f, 0.f, 0.f, 0.f};
#pragma unroll
    for (int it = 0; it < 8; ++it) {
        float4 v = *(const float4*)(rp + it * 256 + lane * 4);
        s4.x += v.x; s4.y += v.y; s4.z += v.z; s4.w += v.w;
    }
    float s = (s4.x + s4.y) + (s4.z + s4.w);
#pragma unroll
    for (int off = 32; off; off >>= 1) s += __shfl_down(s, off);
    if (lane == 0) {
        int n = row & (NN - 1);
        float sh = s - rp[n] + 1.0f;            // zero diag, add self-loop
        dvec[row] = 1.0f / (1e-6f + sqrtf(sh));
    }
}

// ------- K2: yt_t[b][m>>5][o][m&31] = bf16(d[m] * (x@W)[m,o]), LDS-free --
__global__ __launch_bounds__(256) void xw_kernel(const float* __restrict__ x,
                                                 const __bf16* __restrict__ Wt,
                                                 const float* __restrict__ dvec,
                                                 __bf16* __restrict__ yt) {
    const int lane = threadIdx.x & 63;
    const int wave = threadIdx.x >> 6;
    const int b    = blockIdx.x & 7;
    const int mt   = (blockIdx.x >> 3) * 4 + wave;   // 0..127
    const int m0   = mt * 16;
    const int kgrp = (lane >> 4) * 8;
    const float* xp = x + ((size_t)b * NN + m0 + (lane & 15)) * 128 + kgrp;

    f32x4 acc[8];
#pragma unroll
    for (int i = 0; i < 8; ++i) acc[i] = (f32x4){0.f, 0.f, 0.f, 0.f};

#pragma unroll
    for (int kt = 0; kt < 4; ++kt) {
        f32x4 a0 = *(const f32x4*)(xp + kt * 32);
        f32x4 a1 = *(const f32x4*)(xp + kt * 32 + 4);
        float av[8] = {a0.x, a0.y, a0.z, a0.w, a1.x, a1.y, a1.z, a1.w};
        bf16x8 af;
#pragma unroll
        for (int j = 0; j < 8; ++j) af[j] = (__bf16)av[j];
#pragma unroll
        for (int nb = 0; nb < 8; ++nb) {
            bf16x8 bfv = *(const bf16x8*)(Wt + (nb * 16 + (lane & 15)) * 128 +
                                          kt * 32 + kgrp);
            acc[nb] = __builtin_amdgcn_mfma_f32_16x16x32_bf16(af, bfv, acc[nb], 0, 0, 0);
        }
    }
    const int col0 = lane & 15;
    const int rq   = (lane >> 4) * 4;
#pragma unroll
    for (int r = 0; r < 4; ++r) {
        int m = m0 + rq + r;
        float dm = dvec[b * NN + m];
        // tiled: yt_t[b][m>>5][o][m&31]
        __bf16* yrow = yt + (((size_t)b * 64 + (m >> 5)) * 128) * 32 + (m & 31);
#pragma unroll
        for (int nb = 0; nb < 8; ++nb) {
            int o = nb * 16 + col0;
            yrow[(size_t)o * 32] = (__bf16)(acc[nb][r] * dm);
        }
    }
}

// ---------------- K3: staged GEMM, dedup'd 1x4 wave grid ------------------
// Block 256 thr = 4 waves; tile = 64 rows x 128 cols; wave w: rows w*16..+15,
// ALL 128 cols. grid 256 (1 block/CU), b = blockIdx.x & 7.
__global__ __launch_bounds__(256) void gemm_kernel(const float* __restrict__ adj,
                                                   const __bf16* __restrict__ yt,
                                                   const float* __restrict__ dvec,
                                                   float* __restrict__ out) {
    __shared__ alignas(16) __bf16 sB[2][128][32];   // [o][k] image of one tile

    const int tid  = threadIdx.x;
    const int wave = tid >> 6;
    const int lane = tid & 63;
    const int b    = blockIdx.x & 7;
    const int tile = blockIdx.x >> 3;            // 0..31
    const int kgrp = (lane >> 4) * 8;
    const int l15  = lane & 15;

    // A: direct from global fp32, k-contiguous fragment; UNIQUE per wave
    const int arow_loc = tile * 64 + wave * 16 + l15;
    const float* ap = adj + ((size_t)b * NN + arow_loc) * NN + kgrp;

    // B: tiled yt_t[b][kt][o][32]; wave w copies bytes [w*2KB, w*2KB+2KB)
    // of each 8KB tile as two 1-KB CONTIGUOUS glds bursts.
    const __bf16* ytb   = yt + (size_t)b * 64 * 128 * 32;   // batch base
    const __bf16* b_src = ytb + wave * 1024 + lane * 8;     // + kt*4096 (+512)

    f32x4 acc[8];
#pragma unroll
    for (int i = 0; i < 8; ++i) acc[i] = (f32x4){0.f, 0.f, 0.f, 0.f};

    // preload iter 0
    load_lds16(&sB[0][wave * 32][0], b_src);
    load_lds16(&sB[0][wave * 32 + 16][0], b_src + 512);
    f32x4 ca0 = *(const f32x4*)(ap);
    f32x4 ca1 = *(const f32x4*)(ap + 4);

    for (int kt = 0; kt < 64; ++kt) {
        const int cur = kt & 1;
        __syncthreads();   // drains loads issued last iter (glds + A regs)

        // issue NEXT iter's loads first: in flight through the MFMA phase
        f32x4 na0, na1;
        if (kt + 1 < 64) {
            const __bf16* bs = b_src + (size_t)(kt + 1) * 4096;
            load_lds16(&sB[cur ^ 1][wave * 32][0], bs);
            load_lds16(&sB[cur ^ 1][wave * 32 + 16][0], bs + 512);
            na0 = *(const f32x4*)(ap + (kt + 1) * 32);
            na1 = *(const f32x4*)(ap + (kt + 1) * 32 + 4);
        }

        // convert current A regs (loaded last iter, drained by the barrier)
        bf16x8 af;
        af[0] = (__bf16)ca0.x; af[1] = (__bf16)ca0.y;
        af[2] = (__bf16)ca0.z; af[3] = (__bf16)ca0.w;
        af[4] = (__bf16)ca1.x; af[5] = (__bf16)ca1.y;
        af[6] = (__bf16)ca1.z; af[7] = (__bf16)ca1.w;

#pragma unroll
        for (int nb = 0; nb < 8; ++nb) {
            bf16x8 bfv = *(const bf16x8*)(&sB[cur][nb * 16 + l15][kgrp]);
            acc[nb] = __builtin_amdgcn_mfma_f32_16x16x32_bf16(af, bfv, acc[nb], 0, 0, 0);
        }
        ca0 = na0; ca1 = na1;
    }

    // epilogue: diag correction + row scale + relu
    //   out = d[n] * (acc + (1 - adj[n,n]) * yt[o][n])
    const int rq = (lane >> 4) * 4;
#pragma unroll
    for (int r = 0; r < 4; ++r) {
        int n_loc = tile * 64 + wave * 16 + rq + r;
        size_t grow = (size_t)b * NN + n_loc;
        float dn   = dvec[grow];
        float cfac = 1.0f - adj[grow * NN + n_loc];
        const __bf16* ycol = ytb + ((size_t)(n_loc >> 5) * 128) * 32 + (n_loc & 31);
#pragma unroll
        for (int nb = 0; nb < 8; ++nb) {
            int o = nb * 16 + l15;
            float yp = (float)ycol[(size_t)o * 32];
            float v = (acc[nb][r] + cfac * yp) * dn;
            out[grow * 128 + o] = v > 0.f ? v : 0.f;
        }
    }
}

extern "C" void kernel_launch(void* const* d_in, const int* in_sizes, int n_in,
                              void* d_out, int out_size, void* d_ws, size_t ws_size,
                              hipStream_t stream) {
    const float* x   = (const float*)d_in[0];   // [8,2048,128]
    const float* adj = (const float*)d_in[1];   // [8,2048,2048]
    const float* W   = (const float*)d_in[2];   // [128,128]
    float* out = (float*)d_out;

    char* ws = (char*)d_ws;
    float*  dvec = (float*)ws;                          // 64 KB
    __bf16* Wt   = (__bf16*)(ws + (64 << 10));          // 32 KB
    __bf16* yt   = (__bf16*)(ws + (128 << 10));         // 4 MB  [B][64][128][32]

    hipLaunchKernelGGL(d_kernel, dim3(NB * NN / 4 + 64), dim3(256), 0, stream,
                       adj, dvec, W, Wt);
    hipLaunchKernelGGL(xw_kernel, dim3(256), dim3(256), 0, stream, x, Wt, dvec, yt);
    hipLaunchKernelGGL(gemm_kernel, dim3(256), dim3(256), 0, stream,
                       adj, yt, dvec, out);
}